// Round 11
// baseline (538.469 us; speedup 1.0000x reference)
//
#include <hip/hip_runtime.h>

#define D 360
#define NAG 64
#define NB 60
#define NPAN 6
#define STRD 68                 // LDS row stride: 68%32=4 -> banks spread, float4-aligned
#define COV_OFF (NAG * D)
#define INIT_OFF (COV_OFF + NAG * D * D)
// ping-pong R stash in d_ws: [parity][agent][ct 0..5][60][60]  (rows of next panel)
#define RBOFF(par, ag, ct) ((((par) * NAG + (ag)) * 6 + (ct)) * 3600)

__device__ __forceinline__ int gshift(int i) {
    return ((i % 60) < 58) ? (i + 2) : i;
}

// ------- build: S (upd) / final cov (others) + mean/flag + R0 stash (all 6) --
__global__ __launch_bounds__(384) void build_kernel(
    const float* __restrict__ P, const float* __restrict__ mean_in,
    const float* __restrict__ obs, const float* __restrict__ rs,
    const int* __restrict__ init_f, const int* __restrict__ sel_f,
    float* __restrict__ out, float* __restrict__ rb)
{
    const int by = blockIdx.x, ag = blockIdx.y, t = threadIdx.x;
    const bool ini = init_f[ag] != 0, sel = sel_f[ag] != 0;
    const float c = rs[ag] + 1.0f;
    if (by == 45) {   // fused "small" block: mean passthrough/init + flag
        if (t < D) {
            float v = (sel && !ini) ? obs[ag * D + t] : mean_in[ag * D + t];
            out[ag * D + t] = v;     // upd agents overwritten by solve_mean
        }
        if (t == 0) out[INIT_OFF + ag] = (ini || sel) ? 1.0f : 0.0f;
        return;
    }
    if (t >= D) return;
    const float* Pa = P + (size_t)ag * D * D;
    float* cov = out + COV_OFF + (size_t)ag * D * D;
    const int j = t;
    if (sel && ini) {
        const int gj = gshift(j);
        #pragma unroll
        for (int s = 0; s < 8; ++s) {
            const int i = by * 8 + s;
            float v = Pa[(size_t)gshift(i) * D + gj];
            if (i == j) v += 1.0f + c;           // + process(1) + obs(c)
            cov[(size_t)i * D + j] = v;
            if (i < NB)                           // stash ALL 6 R tiles for pass 0
                rb[RBOFF(0, ag, j / NB) + i * NB + (j % NB)] = v;
        }
    } else if (sel) {
        #pragma unroll
        for (int s = 0; s < 8; ++s) {
            const int i = by * 8 + s;
            cov[(size_t)i * D + j] = Pa[(size_t)i * D + j] + ((i == j) ? c : 0.0f);
        }
    } else {
        #pragma unroll
        for (int s = 0; s < 8; ++s) {
            const int i = by * 8 + s;
            cov[(size_t)i * D + j] = Pa[(size_t)i * D + j];
        }
    }
}

// ---------------- 4x4 in-place GJ inverse (no pivoting; SPD blocks) ----------
__device__ __forceinline__ void inv4(float4& m0, float4& m1, float4& m2, float4& m3)
{
    float pv, f;
    pv = 1.0f / m0.x;
    m0.y *= pv; m0.z *= pv; m0.w *= pv; m0.x = pv;
    f = m1.x; m1.y = fmaf(-f, m0.y, m1.y); m1.z = fmaf(-f, m0.z, m1.z); m1.w = fmaf(-f, m0.w, m1.w); m1.x = -f * pv;
    f = m2.x; m2.y = fmaf(-f, m0.y, m2.y); m2.z = fmaf(-f, m0.z, m2.z); m2.w = fmaf(-f, m0.w, m2.w); m2.x = -f * pv;
    f = m3.x; m3.y = fmaf(-f, m0.y, m3.y); m3.z = fmaf(-f, m0.z, m3.z); m3.w = fmaf(-f, m0.w, m3.w); m3.x = -f * pv;
    pv = 1.0f / m1.y;
    m1.x *= pv; m1.z *= pv; m1.w *= pv; m1.y = pv;
    f = m0.y; m0.x = fmaf(-f, m1.x, m0.x); m0.z = fmaf(-f, m1.z, m0.z); m0.w = fmaf(-f, m1.w, m0.w); m0.y = -f * pv;
    f = m2.y; m2.x = fmaf(-f, m1.x, m2.x); m2.z = fmaf(-f, m1.z, m2.z); m2.w = fmaf(-f, m1.w, m2.w); m2.y = -f * pv;
    f = m3.y; m3.x = fmaf(-f, m1.x, m3.x); m3.z = fmaf(-f, m1.z, m3.z); m3.w = fmaf(-f, m1.w, m3.w); m3.y = -f * pv;
    pv = 1.0f / m2.z;
    m2.x *= pv; m2.y *= pv; m2.w *= pv; m2.z = pv;
    f = m0.z; m0.x = fmaf(-f, m2.x, m0.x); m0.y = fmaf(-f, m2.y, m0.y); m0.w = fmaf(-f, m2.w, m0.w); m0.z = -f * pv;
    f = m1.z; m1.x = fmaf(-f, m2.x, m1.x); m1.y = fmaf(-f, m2.y, m1.y); m1.w = fmaf(-f, m2.w, m1.w); m1.z = -f * pv;
    f = m3.z; m3.x = fmaf(-f, m2.x, m3.x); m3.y = fmaf(-f, m2.y, m3.y); m3.w = fmaf(-f, m2.w, m3.w); m3.z = -f * pv;
    pv = 1.0f / m3.w;
    m3.x *= pv; m3.y *= pv; m3.z *= pv; m3.w = pv;
    f = m0.w; m0.x = fmaf(-f, m3.x, m0.x); m0.y = fmaf(-f, m3.y, m0.y); m0.z = fmaf(-f, m3.z, m0.z); m0.w = -f * pv;
    f = m1.w; m1.x = fmaf(-f, m3.x, m1.x); m1.y = fmaf(-f, m3.y, m1.y); m1.z = fmaf(-f, m3.z, m1.z); m1.w = -f * pv;
    f = m2.w; m2.x = fmaf(-f, m3.x, m2.x); m2.y = fmaf(-f, m3.y, m2.y); m2.z = fmaf(-f, m3.z, m2.z); m2.w = -f * pv;
}

__device__ __forceinline__ void mm_row(const float4 a, const float4 b0, const float4 b1,
                                       const float4 b2, const float4 b3, float acc[4]) {
    acc[0] = fmaf(a.x, b0.x, fmaf(a.y, b1.x, fmaf(a.z, b2.x, fmaf(a.w, b3.x, acc[0]))));
    acc[1] = fmaf(a.x, b0.y, fmaf(a.y, b1.y, fmaf(a.z, b2.y, fmaf(a.w, b3.y, acc[1]))));
    acc[2] = fmaf(a.x, b0.z, fmaf(a.y, b1.z, fmaf(a.z, b2.z, fmaf(a.w, b3.z, acc[2]))));
    acc[3] = fmaf(a.x, b0.w, fmaf(a.y, b1.w, fmaf(a.z, b2.w, fmaf(a.w, b3.w, acc[3]))));
}

// ------------------- one full GJ pass in a single dispatch -------------------
// WG (ag, rt, zc): A) Binv in LDS (redundant)  B) F[rt] = +/- R[rt]^T Binv
// C) 2 of 6 jobs: [write panel col M[:,p]=F] + 5x [M[rt,ct] += F*R[ct]].
// All inputs from pass p-1 stash / pre-pass M -> race-free single dispatch.
__global__ __launch_bounds__(256) void pass_kernel(
    float* __restrict__ out, const float* __restrict__ rs,
    const int* __restrict__ init_f, const int* __restrict__ sel_f,
    float* __restrict__ rb, int p)
{
    const int ag = blockIdx.x;
    if (!(init_f[ag] && sel_f[ag])) return;
    const int rt = blockIdx.y;          // row-tile owned by this WG
    const int zc = blockIdx.z;          // job pair
    float* M = out + COV_OFF + (size_t)ag * D * D;
    const float c = rs[ag] + 1.0f;
    const float c2 = c * c;
    const int t = threadIdx.x;
    __shared__ float Bsh[NB][STRD];
    __shared__ float Fsh[NB][STRD];
    __shared__ float Rsh[NB][STRD];
    __shared__ float praw[4][STRD];

    // ---- Phase A: Binv via LDS mb=4 block-GJ (redundant per WG) ----
    {
        const float* bsrc = rb + RBOFF(p & 1, ag, p);
        for (int idx = t; idx < 900; idx += 256) {
            const int r = idx / 15, q = idx % 15;
            *(float4*)&Bsh[r][4 * q] = *(const float4*)(bsrc + r * NB + 4 * q);
        }
        __syncthreads();
        const int r = t >> 2;           // row 0..63 (active < 60)
        const int qt = t & 3;           // column quarter (15 cols each)
        for (int kb = 0; kb < 15; ++kb) {
            for (int idx = t; idx < 240; idx += 256)
                praw[idx / 60][idx % 60] = Bsh[4 * kb + idx / 60][idx % 60];
            __syncthreads();
            float4 m0 = make_float4(praw[0][4*kb], praw[0][4*kb+1], praw[0][4*kb+2], praw[0][4*kb+3]);
            float4 m1 = make_float4(praw[1][4*kb], praw[1][4*kb+1], praw[1][4*kb+2], praw[1][4*kb+3]);
            float4 m2 = make_float4(praw[2][4*kb], praw[2][4*kb+1], praw[2][4*kb+2], praw[2][4*kb+3]);
            float4 m3 = make_float4(praw[3][4*kb], praw[3][4*kb+1], praw[3][4*kb+2], praw[3][4*kb+3]);
            inv4(m0, m1, m2, m3);
            if (r < NB) {
                const int rel = r - 4 * kb;
                const bool ispiv = (rel >= 0 && rel < 4);
                float4 sc;
                if (ispiv) {
                    sc = (rel == 0) ? m0 : (rel == 1) ? m1 : (rel == 2) ? m2 : m3;
                } else {
                    const float4 fr = make_float4(Bsh[r][4*kb], Bsh[r][4*kb+1],
                                                  Bsh[r][4*kb+2], Bsh[r][4*kb+3]);
                    sc.x = -(fr.x * m0.x + fr.y * m1.x + fr.z * m2.x + fr.w * m3.x);
                    sc.y = -(fr.x * m0.y + fr.y * m1.y + fr.z * m2.y + fr.w * m3.y);
                    sc.z = -(fr.x * m0.z + fr.y * m1.z + fr.z * m2.z + fr.w * m3.z);
                    sc.w = -(fr.x * m0.w + fr.y * m1.w + fr.z * m2.w + fr.w * m3.w);
                }
                #pragma unroll
                for (int cc = 0; cc < 15; ++cc) {
                    const int col = qt * 15 + cc;
                    const int pc = col - 4 * kb;
                    if (pc >= 0 && pc < 4) {
                        Bsh[r][col] = (pc == 0) ? sc.x : (pc == 1) ? sc.y : (pc == 2) ? sc.z : sc.w;
                    } else {
                        const float base = ispiv ? 0.0f : Bsh[r][col];
                        Bsh[r][col] = fmaf(sc.x, praw[0][col], fmaf(sc.y, praw[1][col],
                                      fmaf(sc.z, praw[2][col], fmaf(sc.w, praw[3][col], base))));
                    }
                }
            }
            __syncthreads();
        }
    }

    // ---- Phase B: Fsh = (rt==p ? Binv : sgn * R[rt]^T * Binv) ----
    const int tx = t % 16, ty = t / 16;
    if (rt == p) {
        for (int idx = t; idx < 900; idx += 256) {
            const int r = idx / 15, q = idx % 15;
            *(float4*)&Fsh[r][4 * q] = *(const float4*)&Bsh[r][4 * q];
        }
    } else {
        const float sgn = (rt < p) ? 1.0f : -1.0f;    // C[rt] = -sgn * R[rt]^T
        const float* rsrc = rb + RBOFF(p & 1, ag, rt);
        for (int idx = t; idx < 900; idx += 256) {
            const int k = idx / 15, q = idx % 15;
            *(float4*)&Rsh[k][4 * q] = *(const float4*)(rsrc + k * NB + 4 * q);
        }
        __syncthreads();
        if (tx < 15 && ty < 15) {
            float acc[4][4];
            #pragma unroll
            for (int i = 0; i < 4; ++i)
                #pragma unroll
                for (int j = 0; j < 4; ++j) acc[i][j] = 0.0f;
            for (int kq = 0; kq < 15; ++kq) {
                #pragma unroll
                for (int m = 0; m < 4; ++m) {      // A[i][k]=R[k][i]: outer products
                    const float a0 = Rsh[4*kq+m][4*ty+0];
                    const float a1 = Rsh[4*kq+m][4*ty+1];
                    const float a2 = Rsh[4*kq+m][4*ty+2];
                    const float a3 = Rsh[4*kq+m][4*ty+3];
                    const float4 b = *(const float4*)&Bsh[4*kq+m][4*tx];
                    acc[0][0] = fmaf(a0, b.x, acc[0][0]); acc[0][1] = fmaf(a0, b.y, acc[0][1]);
                    acc[0][2] = fmaf(a0, b.z, acc[0][2]); acc[0][3] = fmaf(a0, b.w, acc[0][3]);
                    acc[1][0] = fmaf(a1, b.x, acc[1][0]); acc[1][1] = fmaf(a1, b.y, acc[1][1]);
                    acc[1][2] = fmaf(a1, b.z, acc[1][2]); acc[1][3] = fmaf(a1, b.w, acc[1][3]);
                    acc[2][0] = fmaf(a2, b.x, acc[2][0]); acc[2][1] = fmaf(a2, b.y, acc[2][1]);
                    acc[2][2] = fmaf(a2, b.z, acc[2][2]); acc[2][3] = fmaf(a2, b.w, acc[2][3]);
                    acc[3][0] = fmaf(a3, b.x, acc[3][0]); acc[3][1] = fmaf(a3, b.y, acc[3][1]);
                    acc[3][2] = fmaf(a3, b.z, acc[3][2]); acc[3][3] = fmaf(a3, b.w, acc[3][3]);
                }
            }
            #pragma unroll
            for (int i = 0; i < 4; ++i) {
                float4 v = make_float4(sgn * acc[i][0], sgn * acc[i][1],
                                       sgn * acc[i][2], sgn * acc[i][3]);
                *(float4*)&Fsh[4 * ty + i][4 * tx] = v;
            }
        }
    }
    __syncthreads();

    // ---- Phase C: two jobs from [panel, ct0..ct4] ----
    for (int jj = 2 * zc; jj < 2 * zc + 2; ++jj) {
        if (jj == 0) {
            // panel write: M[rt, p-cols] = F  (+ p5 transform; stash if rt==p+1)
            for (int idx = t; idx < 900; idx += 256) {
                const int r = idx / 15, q = idx % 15;
                float4 v = *(const float4*)&Fsh[r][4 * q];
                const int rg = rt * NB + r;
                float* dst = M + (size_t)rg * D + p * NB + 4 * q;
                if (p == NPAN - 1) {
                    const int cg = p * NB + 4 * q;
                    float4 o;
                    o.x = ((rg == cg + 0) ? c : 0.f) - c2 * v.x;
                    o.y = ((rg == cg + 1) ? c : 0.f) - c2 * v.y;
                    o.z = ((rg == cg + 2) ? c : 0.f) - c2 * v.z;
                    o.w = ((rg == cg + 3) ? c : 0.f) - c2 * v.w;
                    *(float4*)dst = o;
                } else {
                    *(float4*)dst = v;
                    if (rt == p + 1)
                        *(float4*)(rb + RBOFF((p + 1) & 1, ag, p) + r * NB + 4 * q) = v;
                }
            }
        } else {
            const int ci = jj - 1;                    // 0..4
            const int ct = ci + (ci >= p ? 1 : 0);    // skip panel column
            __syncthreads();                          // Rsh free for reuse
            const float* rsrc = rb + RBOFF(p & 1, ag, ct);
            for (int idx = t; idx < 900; idx += 256) {
                const int k = idx / 15, q = idx % 15;
                *(float4*)&Rsh[k][4 * q] = *(const float4*)(rsrc + k * NB + 4 * q);
            }
            __syncthreads();
            if (tx < 15 && ty < 15) {
                float acc[4][4];
                #pragma unroll
                for (int i = 0; i < 4; ++i)
                    #pragma unroll
                    for (int j = 0; j < 4; ++j) acc[i][j] = 0.0f;
                for (int kq = 0; kq < 15; ++kq) {
                    float4 a0 = *(const float4*)&Fsh[4 * ty + 0][4 * kq];
                    float4 a1 = *(const float4*)&Fsh[4 * ty + 1][4 * kq];
                    float4 a2 = *(const float4*)&Fsh[4 * ty + 2][4 * kq];
                    float4 a3 = *(const float4*)&Fsh[4 * ty + 3][4 * kq];
                    float4 b0 = *(const float4*)&Rsh[4 * kq + 0][4 * tx];
                    float4 b1 = *(const float4*)&Rsh[4 * kq + 1][4 * tx];
                    float4 b2 = *(const float4*)&Rsh[4 * kq + 2][4 * tx];
                    float4 b3 = *(const float4*)&Rsh[4 * kq + 3][4 * tx];
                    mm_row(a0, b0, b1, b2, b3, acc[0]);
                    mm_row(a1, b0, b1, b2, b3, acc[1]);
                    mm_row(a2, b0, b1, b2, b3, acc[2]);
                    mm_row(a3, b0, b1, b2, b3, acc[3]);
                }
                #pragma unroll
                for (int i = 0; i < 4; ++i) {
                    const int rg = rt * NB + 4 * ty + i;
                    float* dst = M + (size_t)rg * D + ct * NB + 4 * tx;
                    float4 base;
                    if (rt == p) { base = make_float4(0.f, 0.f, 0.f, 0.f); }
                    else         { base = *(const float4*)dst; }
                    float4 v;
                    v.x = base.x + acc[i][0];
                    v.y = base.y + acc[i][1];
                    v.z = base.z + acc[i][2];
                    v.w = base.w + acc[i][3];
                    if (p < NPAN - 1) {
                        if (rt == p + 1) {   // stash next pass's R slice
                            float* rdst = rb + RBOFF((p + 1) & 1, ag, ct)
                                        + (4 * ty + i) * NB + 4 * tx;
                            *(float4*)rdst = v;
                        }
                        *(float4*)dst = v;
                    } else {                 // fold finalize  cov = c*I - c^2*Sinv
                        const int cg = ct * NB + 4 * tx;
                        float4 o;
                        o.x = ((rg == cg + 0) ? c : 0.f) - c2 * v.x;
                        o.y = ((rg == cg + 1) ? c : 0.f) - c2 * v.y;
                        o.z = ((rg == cg + 2) ? c : 0.f) - c2 * v.z;
                        o.w = ((rg == cg + 3) ? c : 0.f) - c2 * v.w;
                        *(float4*)dst = o;
                    }
                }
            }
        }
    }
}

// ------- mean: m = obs - c*Sinv*d, via transformed C:  m = obs - d + (C^T d)/c
__global__ __launch_bounds__(384) void solve_mean_kernel(
    float* __restrict__ out, const float* __restrict__ mean_in,
    const float* __restrict__ obs, const float* __restrict__ rs,
    const int* __restrict__ init_f, const int* __restrict__ sel_f)
{
    const int ag = blockIdx.x;
    if (!(init_f[ag] && sel_f[ag])) return;
    const float* C = out + COV_OFF + (size_t)ag * D * D;
    __shared__ float dsh[D];
    const int t = threadIdx.x;
    if (t < D) dsh[t] = obs[ag * D + t] - mean_in[ag * D + gshift(t)];
    __syncthreads();
    if (t < D) {
        float dot = 0.0f;
        #pragma unroll 8
        for (int j = 0; j < D; ++j)
            dot = fmaf(C[(size_t)j * D + t], dsh[j], dot);   // coalesced col read
        const float c = rs[ag] + 1.0f;
        out[ag * D + t] = obs[ag * D + t] - dsh[t] + dot / c;
    }
}

extern "C" void kernel_launch(void* const* d_in, const int* in_sizes, int n_in,
                              void* d_out, int out_size, void* d_ws, size_t ws_size,
                              hipStream_t stream) {
    const float* mean_in     = (const float*)d_in[0];
    const float* P           = (const float*)d_in[1];
    const float* obs         = (const float*)d_in[2];
    const float* rs          = (const float*)d_in[3];
    const int*   initialized = (const int*)d_in[4];
    const int*   selected    = (const int*)d_in[5];
    float* out = (float*)d_out;
    float* rb  = (float*)d_ws;   // 2*64*6*3600 floats = 11.06 MB

    build_kernel<<<dim3(46, NAG), 384, 0, stream>>>(P, mean_in, obs, rs,
                                                    initialized, selected, out, rb);
    for (int p = 0; p < NPAN; ++p)
        pass_kernel<<<dim3(NAG, NPAN, 3), 256, 0, stream>>>(out, rs, initialized,
                                                            selected, rb, p);
    solve_mean_kernel<<<NAG, 384, 0, stream>>>(out, mean_in, obs, rs, initialized, selected);
}

// Round 12
// 336.762 us; speedup vs baseline: 1.5990x; 1.5990x over previous
//
#include <hip/hip_runtime.h>

#define D 360
#define NAG 64
#define NB 60
#define NPAN 6
#define STRD 68                 // LDS row stride: float4-aligned, spreads banks
#define COV_OFF (NAG * D)
#define INIT_OFF (COV_OFF + NAG * D * D)
// ping-pong R stash in d_ws: [parity][agent][ct 0..5][60][60]  (rows of next panel)
#define RBOFF(par, ag, ct) ((((par) * NAG + (ag)) * 6 + (ct)) * 3600)
// Binv stash: [agent][60][60]
#define BVOFF(ag) (2764800 + (ag) * 3600)

__device__ __forceinline__ int gshift(int i) {
    return ((i % 60) < 58) ? (i + 2) : i;
}

// ------- build: S (upd) / final cov (others) + mean/flag + R0 stash (all 6) --
__global__ __launch_bounds__(384) void build_kernel(
    const float* __restrict__ P, const float* __restrict__ mean_in,
    const float* __restrict__ obs, const float* __restrict__ rs,
    const int* __restrict__ init_f, const int* __restrict__ sel_f,
    float* __restrict__ out, float* __restrict__ rb)
{
    const int by = blockIdx.x, ag = blockIdx.y, t = threadIdx.x;
    const bool ini = init_f[ag] != 0, sel = sel_f[ag] != 0;
    const float c = rs[ag] + 1.0f;
    if (by == 45) {   // fused "small" block: mean passthrough/init + flag
        if (t < D) {
            float v = (sel && !ini) ? obs[ag * D + t] : mean_in[ag * D + t];
            out[ag * D + t] = v;     // upd agents overwritten by solve_mean
        }
        if (t == 0) out[INIT_OFF + ag] = (ini || sel) ? 1.0f : 0.0f;
        return;
    }
    if (t >= D) return;
    const float* Pa = P + (size_t)ag * D * D;
    float* cov = out + COV_OFF + (size_t)ag * D * D;
    const int j = t;
    if (sel && ini) {
        const int gj = gshift(j);
        #pragma unroll
        for (int s = 0; s < 8; ++s) {
            const int i = by * 8 + s;
            float v = Pa[(size_t)gshift(i) * D + gj];
            if (i == j) v += 1.0f + c;           // + process(1) + obs(c)
            cov[(size_t)i * D + j] = v;
            if (i < NB)                           // stash ALL 6 R tiles for pass 0
                rb[RBOFF(0, ag, j / NB) + i * NB + (j % NB)] = v;
        }
    } else if (sel) {
        #pragma unroll
        for (int s = 0; s < 8; ++s) {
            const int i = by * 8 + s;
            cov[(size_t)i * D + j] = Pa[(size_t)i * D + j] + ((i == j) ? c : 0.0f);
        }
    } else {
        #pragma unroll
        for (int s = 0; s < 8; ++s) {
            const int i = by * 8 + s;
            cov[(size_t)i * D + j] = Pa[(size_t)i * D + j];
        }
    }
}

// ---------------- 4x4 in-place GJ inverse (no pivoting; SPD blocks) ----------
__device__ __forceinline__ void inv4(float4& m0, float4& m1, float4& m2, float4& m3)
{
    float pv, f;
    pv = 1.0f / m0.x;
    m0.y *= pv; m0.z *= pv; m0.w *= pv; m0.x = pv;
    f = m1.x; m1.y = fmaf(-f, m0.y, m1.y); m1.z = fmaf(-f, m0.z, m1.z); m1.w = fmaf(-f, m0.w, m1.w); m1.x = -f * pv;
    f = m2.x; m2.y = fmaf(-f, m0.y, m2.y); m2.z = fmaf(-f, m0.z, m2.z); m2.w = fmaf(-f, m0.w, m2.w); m2.x = -f * pv;
    f = m3.x; m3.y = fmaf(-f, m0.y, m3.y); m3.z = fmaf(-f, m0.z, m3.z); m3.w = fmaf(-f, m0.w, m3.w); m3.x = -f * pv;
    pv = 1.0f / m1.y;
    m1.x *= pv; m1.z *= pv; m1.w *= pv; m1.y = pv;
    f = m0.y; m0.x = fmaf(-f, m1.x, m0.x); m0.z = fmaf(-f, m1.z, m0.z); m0.w = fmaf(-f, m1.w, m0.w); m0.y = -f * pv;
    f = m2.y; m2.x = fmaf(-f, m1.x, m2.x); m2.z = fmaf(-f, m1.z, m2.z); m2.w = fmaf(-f, m1.w, m2.w); m2.y = -f * pv;
    f = m3.y; m3.x = fmaf(-f, m1.x, m3.x); m3.z = fmaf(-f, m1.z, m3.z); m3.w = fmaf(-f, m1.w, m3.w); m3.y = -f * pv;
    pv = 1.0f / m2.z;
    m2.x *= pv; m2.y *= pv; m2.w *= pv; m2.z = pv;
    f = m0.z; m0.x = fmaf(-f, m2.x, m0.x); m0.y = fmaf(-f, m2.y, m0.y); m0.w = fmaf(-f, m2.w, m0.w); m0.z = -f * pv;
    f = m1.z; m1.x = fmaf(-f, m2.x, m1.x); m1.y = fmaf(-f, m2.y, m1.y); m1.w = fmaf(-f, m2.w, m1.w); m1.z = -f * pv;
    f = m3.z; m3.x = fmaf(-f, m2.x, m3.x); m3.y = fmaf(-f, m2.y, m3.y); m3.w = fmaf(-f, m2.w, m3.w); m3.z = -f * pv;
    pv = 1.0f / m3.w;
    m3.x *= pv; m3.y *= pv; m3.z *= pv; m3.w = pv;
    f = m0.w; m0.x = fmaf(-f, m3.x, m0.x); m0.y = fmaf(-f, m3.y, m0.y); m0.z = fmaf(-f, m3.z, m0.z); m0.w = -f * pv;
    f = m1.w; m1.x = fmaf(-f, m3.x, m1.x); m1.y = fmaf(-f, m3.y, m1.y); m1.z = fmaf(-f, m3.z, m1.z); m1.w = -f * pv;
    f = m2.w; m2.x = fmaf(-f, m3.x, m2.x); m2.y = fmaf(-f, m3.y, m2.y); m2.z = fmaf(-f, m3.z, m2.z); m2.w = -f * pv;
}

// -------- in-WG 60x60 GJ inverse on an LDS tile (256 threads, in place) -----
__device__ __forceinline__ void lds_gj_inverse(float (&Bsh)[NB][STRD],
                                               float (&praw)[4][STRD], int t)
{
    const int r = t >> 2;           // row 0..63 (active < 60)
    const int qt = t & 3;           // column quarter (15 cols)
    for (int kb = 0; kb < 15; ++kb) {
        for (int idx = t; idx < 240; idx += 256)
            praw[idx / 60][idx % 60] = Bsh[4 * kb + idx / 60][idx % 60];
        __syncthreads();
        float4 m0 = make_float4(praw[0][4*kb], praw[0][4*kb+1], praw[0][4*kb+2], praw[0][4*kb+3]);
        float4 m1 = make_float4(praw[1][4*kb], praw[1][4*kb+1], praw[1][4*kb+2], praw[1][4*kb+3]);
        float4 m2 = make_float4(praw[2][4*kb], praw[2][4*kb+1], praw[2][4*kb+2], praw[2][4*kb+3]);
        float4 m3 = make_float4(praw[3][4*kb], praw[3][4*kb+1], praw[3][4*kb+2], praw[3][4*kb+3]);
        inv4(m0, m1, m2, m3);
        if (r < NB) {
            const int rel = r - 4 * kb;
            const bool ispiv = (rel >= 0 && rel < 4);
            float4 sc;
            if (ispiv) {
                sc = (rel == 0) ? m0 : (rel == 1) ? m1 : (rel == 2) ? m2 : m3;
            } else {
                const float4 fr = make_float4(Bsh[r][4*kb], Bsh[r][4*kb+1],
                                              Bsh[r][4*kb+2], Bsh[r][4*kb+3]);
                sc.x = -(fr.x * m0.x + fr.y * m1.x + fr.z * m2.x + fr.w * m3.x);
                sc.y = -(fr.x * m0.y + fr.y * m1.y + fr.z * m2.y + fr.w * m3.y);
                sc.z = -(fr.x * m0.z + fr.y * m1.z + fr.z * m2.z + fr.w * m3.z);
                sc.w = -(fr.x * m0.w + fr.y * m1.w + fr.z * m2.w + fr.w * m3.w);
            }
            #pragma unroll
            for (int cc = 0; cc < 15; ++cc) {
                const int col = qt * 15 + cc;
                const int pc = col - 4 * kb;
                if (pc >= 0 && pc < 4) {
                    Bsh[r][col] = (pc == 0) ? sc.x : (pc == 1) ? sc.y : (pc == 2) ? sc.z : sc.w;
                } else {
                    const float base = ispiv ? 0.0f : Bsh[r][col];
                    Bsh[r][col] = fmaf(sc.x, praw[0][col], fmaf(sc.y, praw[1][col],
                                  fmaf(sc.z, praw[2][col], fmaf(sc.w, praw[3][col], base))));
                }
            }
        }
        __syncthreads();
    }
}

// -------- diag0: prime the Binv pipeline for pass 0 -------------------------
__global__ __launch_bounds__(256) void diag0_kernel(
    const int* __restrict__ init_f, const int* __restrict__ sel_f,
    float* __restrict__ rb)
{
    const int ag = blockIdx.x;
    if (!(init_f[ag] && sel_f[ag])) return;
    const int t = threadIdx.x;
    __shared__ float Bsh[NB][STRD];
    __shared__ float praw[4][STRD];
    const float* bsrc = rb + RBOFF(0, ag, 0);
    for (int idx = t; idx < 900; idx += 256) {
        const int r = idx / 15, q = idx % 15;
        *(float4*)&Bsh[r][4 * q] = *(const float4*)(bsrc + r * NB + 4 * q);
    }
    __syncthreads();
    lds_gj_inverse(Bsh, praw, t);
    float* bdst = rb + BVOFF(ag);
    for (int idx = t; idx < 900; idx += 256) {
        const int r = idx / 15, q = idx % 15;
        *(float4*)(bdst + r * NB + 4 * q) = *(const float4*)&Bsh[r][4 * q];
    }
}

__device__ __forceinline__ void mm_row(const float4 a, const float4 b0, const float4 b1,
                                       const float4 b2, const float4 b3, float acc[4]) {
    acc[0] = fmaf(a.x, b0.x, fmaf(a.y, b1.x, fmaf(a.z, b2.x, fmaf(a.w, b3.x, acc[0]))));
    acc[1] = fmaf(a.x, b0.y, fmaf(a.y, b1.y, fmaf(a.z, b2.y, fmaf(a.w, b3.y, acc[1]))));
    acc[2] = fmaf(a.x, b0.z, fmaf(a.y, b1.z, fmaf(a.z, b2.z, fmaf(a.w, b3.z, acc[2]))));
    acc[3] = fmaf(a.x, b0.w, fmaf(a.y, b1.w, fmaf(a.z, b2.w, fmaf(a.w, b3.w, acc[3]))));
}

// ------------------- one full GJ pass in a single dispatch -------------------
// WG (ag, rt, zc): Binv loaded from stash (computed by pass p-1's owner WG or
// diag0). F[rt] = +/- R[rt]^T Binv. Then 2 of 6 jobs. The WG whose job is
// tile (p+1, p+1) additionally GJ-inverts that tile in LDS and stashes
// Binv for pass p+1 (once per agent, overlapped with other WGs' jobs).
__global__ __launch_bounds__(256) void pass_kernel(
    float* __restrict__ out, const float* __restrict__ rs,
    const int* __restrict__ init_f, const int* __restrict__ sel_f,
    float* __restrict__ rb, int p)
{
    const int ag = blockIdx.x;
    if (!(init_f[ag] && sel_f[ag])) return;
    const int rt = blockIdx.y;          // row-tile owned by this WG
    const int zc = blockIdx.z;          // job pair
    float* M = out + COV_OFF + (size_t)ag * D * D;
    const float c = rs[ag] + 1.0f;
    const float c2 = c * c;
    const int t = threadIdx.x;
    const bool special = (p < NPAN - 1) && (rt == p + 1) && (zc == ((p + 1) >> 1));
    __shared__ float Bsh[NB][STRD];
    __shared__ float Fsh[NB][STRD];
    __shared__ float Rsh[NB][STRD];
    __shared__ float praw[4][STRD];

    // ---- load Binv from stash ----
    {
        const float* bsrc = rb + BVOFF(ag);
        for (int idx = t; idx < 900; idx += 256) {
            const int r = idx / 15, q = idx % 15;
            *(float4*)&Bsh[r][4 * q] = *(const float4*)(bsrc + r * NB + 4 * q);
        }
    }
    __syncthreads();

    // ---- Phase B: Fsh = (rt==p ? Binv : sgn * R[rt]^T * Binv) ----
    const int tx = t % 16, ty = t / 16;
    if (rt == p) {
        for (int idx = t; idx < 900; idx += 256) {
            const int r = idx / 15, q = idx % 15;
            *(float4*)&Fsh[r][4 * q] = *(const float4*)&Bsh[r][4 * q];
        }
    } else {
        const float sgn = (rt < p) ? 1.0f : -1.0f;    // C[rt] = -sgn * R[rt]^T
        const float* rsrc = rb + RBOFF(p & 1, ag, rt);
        for (int idx = t; idx < 900; idx += 256) {
            const int k = idx / 15, q = idx % 15;
            *(float4*)&Rsh[k][4 * q] = *(const float4*)(rsrc + k * NB + 4 * q);
        }
        __syncthreads();
        if (tx < 15 && ty < 15) {
            float acc[4][4];
            #pragma unroll
            for (int i = 0; i < 4; ++i)
                #pragma unroll
                for (int j = 0; j < 4; ++j) acc[i][j] = 0.0f;
            for (int kq = 0; kq < 15; ++kq) {
                #pragma unroll
                for (int m = 0; m < 4; ++m) {      // A[i][k]=R[k][i]: outer products
                    const float a0 = Rsh[4*kq+m][4*ty+0];
                    const float a1 = Rsh[4*kq+m][4*ty+1];
                    const float a2 = Rsh[4*kq+m][4*ty+2];
                    const float a3 = Rsh[4*kq+m][4*ty+3];
                    const float4 b = *(const float4*)&Bsh[4*kq+m][4*tx];
                    acc[0][0] = fmaf(a0, b.x, acc[0][0]); acc[0][1] = fmaf(a0, b.y, acc[0][1]);
                    acc[0][2] = fmaf(a0, b.z, acc[0][2]); acc[0][3] = fmaf(a0, b.w, acc[0][3]);
                    acc[1][0] = fmaf(a1, b.x, acc[1][0]); acc[1][1] = fmaf(a1, b.y, acc[1][1]);
                    acc[1][2] = fmaf(a1, b.z, acc[1][2]); acc[1][3] = fmaf(a1, b.w, acc[1][3]);
                    acc[2][0] = fmaf(a2, b.x, acc[2][0]); acc[2][1] = fmaf(a2, b.y, acc[2][1]);
                    acc[2][2] = fmaf(a2, b.z, acc[2][2]); acc[2][3] = fmaf(a2, b.w, acc[2][3]);
                    acc[3][0] = fmaf(a3, b.x, acc[3][0]); acc[3][1] = fmaf(a3, b.y, acc[3][1]);
                    acc[3][2] = fmaf(a3, b.z, acc[3][2]); acc[3][3] = fmaf(a3, b.w, acc[3][3]);
                }
            }
            #pragma unroll
            for (int i = 0; i < 4; ++i) {
                float4 v = make_float4(sgn * acc[i][0], sgn * acc[i][1],
                                       sgn * acc[i][2], sgn * acc[i][3]);
                *(float4*)&Fsh[4 * ty + i][4 * tx] = v;
            }
        }
    }
    __syncthreads();

    // ---- Phase C: two jobs from [panel, ct0..ct4] ----
    for (int jj = 2 * zc; jj < 2 * zc + 2; ++jj) {
        if (jj == 0) {
            // panel write: M[rt, p-cols] = F  (+ p5 transform; stash if rt==p+1)
            for (int idx = t; idx < 900; idx += 256) {
                const int r = idx / 15, q = idx % 15;
                float4 v = *(const float4*)&Fsh[r][4 * q];
                const int rg = rt * NB + r;
                float* dst = M + (size_t)rg * D + p * NB + 4 * q;
                if (p == NPAN - 1) {
                    const int cg = p * NB + 4 * q;
                    float4 o;
                    o.x = ((rg == cg + 0) ? c : 0.f) - c2 * v.x;
                    o.y = ((rg == cg + 1) ? c : 0.f) - c2 * v.y;
                    o.z = ((rg == cg + 2) ? c : 0.f) - c2 * v.z;
                    o.w = ((rg == cg + 3) ? c : 0.f) - c2 * v.w;
                    *(float4*)dst = o;
                } else {
                    *(float4*)dst = v;
                    if (rt == p + 1)
                        *(float4*)(rb + RBOFF((p + 1) & 1, ag, p) + r * NB + 4 * q) = v;
                }
            }
        } else {
            const int ci = jj - 1;                    // 0..4
            const int ct = ci + (ci >= p ? 1 : 0);    // skip panel column
            __syncthreads();                          // Rsh free for reuse
            const float* rsrc = rb + RBOFF(p & 1, ag, ct);
            for (int idx = t; idx < 900; idx += 256) {
                const int k = idx / 15, q = idx % 15;
                *(float4*)&Rsh[k][4 * q] = *(const float4*)(rsrc + k * NB + 4 * q);
            }
            __syncthreads();
            if (tx < 15 && ty < 15) {
                float acc[4][4];
                #pragma unroll
                for (int i = 0; i < 4; ++i)
                    #pragma unroll
                    for (int j = 0; j < 4; ++j) acc[i][j] = 0.0f;
                for (int kq = 0; kq < 15; ++kq) {
                    float4 a0 = *(const float4*)&Fsh[4 * ty + 0][4 * kq];
                    float4 a1 = *(const float4*)&Fsh[4 * ty + 1][4 * kq];
                    float4 a2 = *(const float4*)&Fsh[4 * ty + 2][4 * kq];
                    float4 a3 = *(const float4*)&Fsh[4 * ty + 3][4 * kq];
                    float4 b0 = *(const float4*)&Rsh[4 * kq + 0][4 * tx];
                    float4 b1 = *(const float4*)&Rsh[4 * kq + 1][4 * tx];
                    float4 b2 = *(const float4*)&Rsh[4 * kq + 2][4 * tx];
                    float4 b3 = *(const float4*)&Rsh[4 * kq + 3][4 * tx];
                    mm_row(a0, b0, b1, b2, b3, acc[0]);
                    mm_row(a1, b0, b1, b2, b3, acc[1]);
                    mm_row(a2, b0, b1, b2, b3, acc[2]);
                    mm_row(a3, b0, b1, b2, b3, acc[3]);
                }
                #pragma unroll
                for (int i = 0; i < 4; ++i) {
                    const int rg = rt * NB + 4 * ty + i;
                    float* dst = M + (size_t)rg * D + ct * NB + 4 * tx;
                    float4 base;
                    if (rt == p) { base = make_float4(0.f, 0.f, 0.f, 0.f); }
                    else         { base = *(const float4*)dst; }
                    float4 v;
                    v.x = base.x + acc[i][0];
                    v.y = base.y + acc[i][1];
                    v.z = base.z + acc[i][2];
                    v.w = base.w + acc[i][3];
                    if (p < NPAN - 1) {
                        if (rt == p + 1) {   // stash next pass's R slice
                            float* rdst = rb + RBOFF((p + 1) & 1, ag, ct)
                                        + (4 * ty + i) * NB + 4 * tx;
                            *(float4*)rdst = v;
                        }
                        *(float4*)dst = v;
                        if (special && ct == p + 1)   // capture next diag tile
                            *(float4*)&Bsh[4 * ty + i][4 * tx] = v;
                    } else {                 // fold finalize  cov = c*I - c^2*Sinv
                        const int cg = ct * NB + 4 * tx;
                        float4 o;
                        o.x = ((rg == cg + 0) ? c : 0.f) - c2 * v.x;
                        o.y = ((rg == cg + 1) ? c : 0.f) - c2 * v.y;
                        o.z = ((rg == cg + 2) ? c : 0.f) - c2 * v.z;
                        o.w = ((rg == cg + 3) ? c : 0.f) - c2 * v.w;
                        *(float4*)dst = o;
                    }
                }
            }
        }
    }

    // ---- special WG: invert the captured (p+1,p+1) tile, stash for pass p+1 --
    if (special) {
        __syncthreads();
        lds_gj_inverse(Bsh, praw, t);
        float* bdst = rb + BVOFF(ag);
        for (int idx = t; idx < 900; idx += 256) {
            const int r = idx / 15, q = idx % 15;
            *(float4*)(bdst + r * NB + 4 * q) = *(const float4*)&Bsh[r][4 * q];
        }
    }
}

// ------- mean: m = obs - c*Sinv*d, via transformed C:  m = obs - d + (C^T d)/c
__global__ __launch_bounds__(384) void solve_mean_kernel(
    float* __restrict__ out, const float* __restrict__ mean_in,
    const float* __restrict__ obs, const float* __restrict__ rs,
    const int* __restrict__ init_f, const int* __restrict__ sel_f)
{
    const int ag = blockIdx.x;
    if (!(init_f[ag] && sel_f[ag])) return;
    const float* C = out + COV_OFF + (size_t)ag * D * D;
    __shared__ float dsh[D];
    const int t = threadIdx.x;
    if (t < D) dsh[t] = obs[ag * D + t] - mean_in[ag * D + gshift(t)];
    __syncthreads();
    if (t < D) {
        float dot = 0.0f;
        #pragma unroll 8
        for (int j = 0; j < D; ++j)
            dot = fmaf(C[(size_t)j * D + t], dsh[j], dot);   // coalesced col read
        const float c = rs[ag] + 1.0f;
        out[ag * D + t] = obs[ag * D + t] - dsh[t] + dot / c;
    }
}

extern "C" void kernel_launch(void* const* d_in, const int* in_sizes, int n_in,
                              void* d_out, int out_size, void* d_ws, size_t ws_size,
                              hipStream_t stream) {
    const float* mean_in     = (const float*)d_in[0];
    const float* P           = (const float*)d_in[1];
    const float* obs         = (const float*)d_in[2];
    const float* rs          = (const float*)d_in[3];
    const int*   initialized = (const int*)d_in[4];
    const int*   selected    = (const int*)d_in[5];
    float* out = (float*)d_out;
    float* rb  = (float*)d_ws;   // R stash 11.06 MB + Binv stash 0.92 MB

    build_kernel<<<dim3(46, NAG), 384, 0, stream>>>(P, mean_in, obs, rs,
                                                    initialized, selected, out, rb);
    diag0_kernel<<<NAG, 256, 0, stream>>>(initialized, selected, rb);
    for (int p = 0; p < NPAN; ++p)
        pass_kernel<<<dim3(NAG, NPAN, 3), 256, 0, stream>>>(out, rs, initialized,
                                                            selected, rb, p);
    solve_mean_kernel<<<NAG, 384, 0, stream>>>(out, mean_in, obs, rs, initialized, selected);
}